// Round 4
// baseline (108.702 us; speedup 1.0000x reference)
//
#include <hip/hip_runtime.h>
#include <hip/hip_bf16.h>

// N=10000 nodes, F=256, H=256, E=320000 edges.
//
// W1 = [W1a | W1b]:  U' = x @ W1a^T + b1 (bias folded), V = x @ W1b^T
// out[e] = sigmoid(b2 + sum_j relu(U'[row][j] + V[col][j]) * W2[j])
// uv layout (fp8 e4m3, HW cvt): uv[node] = 512 bytes: [0:256]=U', [256:512]=V.
//
// R19 = R18 W1-in-LDS structure with REBALANCED, REUSE-MAXIMIZED phase 2:
//   R18 defects: (a) 20 tasks / 16 waves = 62.5% wave utilization;
//   (b) 1.25 frag-loads per MFMA (4 W + 1 x per 4 MFMA) = 640 ds_read_b128
//   per block ~ 7.7k cyc on the LDS port (binding; MFMA only ~3.1k).
//   R19: task = 48 nodes x 64 rows (3 node-subtiles x 4 row-tiles):
//   each W-frag feeds 3 MFMA, each x-frag feeds 4 -> 0.58 frag/MFMA,
//   LDS reads 640 -> 256 per block. Group = 6 tiles (96 nodes) -> 8 tasks
//   on 8 waves (512 thr) = 100% balance. Grid = 105 groups x 2 halves =
//   210 blocks (1 per CU). MFMA operand values/order per output unchanged
//   -> bit-identical (absmax 0.0078125).
//
// Journal: R6+R14 fused coop kernel -> 288/250us (spill/latency-parked).
// R8/R9 sort-for-locality -> 75-96us sort >> gain. R7 deeper edge ILP ->
// neutral (edge random-line-bound ~25us: 164MB @ ~6.5TB/s effective).
// R11 fp8 uv: -14.7us. R12 gemm+1gap = 28us. R13 1-barrier+2x blocks: -3us.
// R15 operand-swap + packed stores: 110.8. R16 folded-h 625x256: 115.3.
// R17 625x512: 114.9 (grid granularity, not waves). R18 W1-in-LDS +
// convert_w eliminated: 106.2 (gain ~= convert+gap only; gemm body ~flat).
// Harness tax ~47-65us fill/restores per window (not controllable).

typedef __attribute__((ext_vector_type(8))) short bf16x8;
typedef __attribute__((ext_vector_type(8))) unsigned short u16x8;
typedef __attribute__((ext_vector_type(4))) float f32x4;
typedef __attribute__((ext_vector_type(2))) float f32x2;

__device__ __forceinline__ unsigned short f2bf(float f) {
    __hip_bfloat16 h = __float2bfloat16(f);
    return *reinterpret_cast<unsigned short*>(&h);
}

// ---------------------------------------------------------------------------
// Kernel 1 (R19): grid 210 = 105 groups x 2 k-halves, block 512 thr (8 waves).
// Phase 1: convert W1[0:256][h*256 .. +256] fp32 -> bf16 into LDS
//          Ws[256][264] (135.2 KB; 264-elem row stride: read pattern proven
//          conflict-free within 8-lane groups).
//          Thread t: row t>>1, cols (t&1)*128 .. +127 (16 vec8 writes).
// Phase 2: 8 tasks on 8 waves, barrier-free. Wave w: tri=w&1, q=w>>1.
//   Task: nodes nb = g*96 + tri*48 (3 subtiles of 16), rows r0 = q*64 (4 j).
//   Per kt (8 total): 3 x-frags (global fp32 -> cvt bf16), 4 W-frags (LDS),
//   12 MFMA acc[j][s] += mfma(wf[j], xf[s]).   96 MFMA/task.
//   W-frag: Ws[r0 + j*16 + lm][kt*32 + lq*8]          (ds_read_b128)
//   x-frag: x[nb + s*16 + lm][kt*32 + lq*8 .. +7]     (2x dwordx4 + cvt)
// Epilogue: bias (h==0, hoisted per j) + 2x cvt_pk_fp8 -> dword store per
//   (j, s):  uv[node*512 + h*256 + r0 + j*16 + lq*4].
// ---------------------------------------------------------------------------
__global__ __launch_bounds__(512) void gemm_lds(const float* __restrict__ x,
                                                const float* __restrict__ w1,
                                                const float* __restrict__ b1,
                                                unsigned char* __restrict__ uv,
                                                int M) {
    __shared__ __align__(16) unsigned short Ws[256][264];   // 135.2 KB

    const int t    = threadIdx.x;
    const int wave = t >> 6;
    const int lane = t & 63;
    const int lm   = lane & 15;
    const int lq   = lane >> 4;
    const int h    = blockIdx.x & 1;       // k-half
    const int g    = blockIdx.x >> 1;      // node group 0..104 (6 tiles each)

    // ---- phase 1: fill Ws. thread t: row t>>1, cols (t&1)*128 .. +127 ----
    {
        const int row  = t >> 1;
        const int col0 = (t & 1) * 128;
        const float* wr = w1 + (size_t)row * 512 + h * 256 + col0;
#pragma unroll
        for (int i = 0; i < 16; ++i) {     // 8 floats -> one 16B LDS write
            float4 a = *(const float4*)(wr + i * 8);
            float4 b = *(const float4*)(wr + i * 8 + 4);
            u16x8 o = {f2bf(a.x), f2bf(a.y), f2bf(a.z), f2bf(a.w),
                       f2bf(b.x), f2bf(b.y), f2bf(b.z), f2bf(b.w)};
            *(u16x8*)&Ws[row][col0 + i * 8] = o;
        }
    }
    __syncthreads();

    // ---- phase 2: one task per wave (perfect balance) ----
    const int tri = wave & 1;              // which 48-node triple
    const int q   = wave >> 1;             // row quarter
    const int r0  = q * 64;
    const int nb  = g * 96 + tri * 48;     // node base of the 3 subtiles

    const float* xr0;
    const float* xr1;
    const float* xr2;
    {
        int g0 = nb + 0 * 16 + lm;  g0 = g0 < M ? g0 : (M - 1);
        int g1 = nb + 1 * 16 + lm;  g1 = g1 < M ? g1 : (M - 1);
        int g2 = nb + 2 * 16 + lm;  g2 = g2 < M ? g2 : (M - 1);
        xr0 = x + (size_t)g0 * 256 + lq * 8;
        xr1 = x + (size_t)g1 * 256 + lq * 8;
        xr2 = x + (size_t)g2 * 256 + lq * 8;
    }

    f32x4 acc[4][3];
#pragma unroll
    for (int j = 0; j < 4; ++j)
#pragma unroll
        for (int s = 0; s < 3; ++s) acc[j][s] = f32x4{0.f, 0.f, 0.f, 0.f};

#pragma unroll 2
    for (int kt = 0; kt < 8; ++kt) {
        bf16x8 xf0, xf1, xf2;
        {
            float4 a = *(const float4*)(xr0 + kt * 32);
            float4 b = *(const float4*)(xr0 + kt * 32 + 4);
            xf0[0] = (short)f2bf(a.x); xf0[1] = (short)f2bf(a.y);
            xf0[2] = (short)f2bf(a.z); xf0[3] = (short)f2bf(a.w);
            xf0[4] = (short)f2bf(b.x); xf0[5] = (short)f2bf(b.y);
            xf0[6] = (short)f2bf(b.z); xf0[7] = (short)f2bf(b.w);
        }
        {
            float4 a = *(const float4*)(xr1 + kt * 32);
            float4 b = *(const float4*)(xr1 + kt * 32 + 4);
            xf1[0] = (short)f2bf(a.x); xf1[1] = (short)f2bf(a.y);
            xf1[2] = (short)f2bf(a.z); xf1[3] = (short)f2bf(a.w);
            xf1[4] = (short)f2bf(b.x); xf1[5] = (short)f2bf(b.y);
            xf1[6] = (short)f2bf(b.z); xf1[7] = (short)f2bf(b.w);
        }
        {
            float4 a = *(const float4*)(xr2 + kt * 32);
            float4 b = *(const float4*)(xr2 + kt * 32 + 4);
            xf2[0] = (short)f2bf(a.x); xf2[1] = (short)f2bf(a.y);
            xf2[2] = (short)f2bf(a.z); xf2[3] = (short)f2bf(a.w);
            xf2[4] = (short)f2bf(b.x); xf2[5] = (short)f2bf(b.y);
            xf2[6] = (short)f2bf(b.z); xf2[7] = (short)f2bf(b.w);
        }
#pragma unroll
        for (int j = 0; j < 4; ++j) {
            bf16x8 wf = *(const bf16x8*)&Ws[r0 + j * 16 + lm][kt * 32 + lq * 8];
            // swapped: A = W1 (m = uv col), B = x (n = node)
            acc[j][0] = __builtin_amdgcn_mfma_f32_16x16x32_bf16(wf, xf0, acc[j][0], 0, 0, 0);
            acc[j][1] = __builtin_amdgcn_mfma_f32_16x16x32_bf16(wf, xf1, acc[j][1], 0, 0, 0);
            acc[j][2] = __builtin_amdgcn_mfma_f32_16x16x32_bf16(wf, xf2, acc[j][2], 0, 0, 0);
        }
    }

    // ---- epilogue: bias hoisted per j; dword store per (j, s) ----
    float4 bb[4];
#pragma unroll
    for (int j = 0; j < 4; ++j)
        bb[j] = (h == 0) ? *(const float4*)(b1 + r0 + j * 16 + lq * 4)
                         : float4{0.f, 0.f, 0.f, 0.f};

#pragma unroll
    for (int s = 0; s < 3; ++s) {
        const int node = nb + s * 16 + lm;
        if (node < M) {
            unsigned char* up = uv + (size_t)node * 512 + h * 256 + r0 + lq * 4;
#pragma unroll
            for (int j = 0; j < 4; ++j) {
                unsigned int d = __builtin_amdgcn_cvt_pk_fp8_f32(
                    acc[j][s][0] + bb[j].x, acc[j][s][1] + bb[j].y, 0, false);
                d = __builtin_amdgcn_cvt_pk_fp8_f32(
                    acc[j][s][2] + bb[j].z, acc[j][s][3] + bb[j].w, d, true);
                *(unsigned int*)(up + j * 16) = d;
            }
        }
    }
}

// ---------------------------------------------------------------------------
// Kernel 2 (R11, unchanged): edge phase over fp8 uv. 4 edges/batch
// (g=lane>>4 slot, c=lane&15 col chunk); per lane one uint4 (16 fp8) per
// U row + one per V row; two independent batches per iteration; HW decode.
// ---------------------------------------------------------------------------
__global__ __launch_bounds__(256) void edge_kernel(const unsigned char* __restrict__ uv,
                                                   const int* __restrict__ ei,
                                                   const float* __restrict__ w2,
                                                   const float* __restrict__ b2p,
                                                   float* __restrict__ out, int E) {
    const int lane = threadIdx.x & 63;
    const int g = lane >> 4;
    const int c = lane & 15;
    const int wid  = (blockIdx.x * blockDim.x + threadIdx.x) >> 6;
    const int nwav = (gridDim.x * blockDim.x) >> 6;
    const int nb   = E >> 2;

    float w2r[16];
#pragma unroll
    for (int i = 0; i < 4; ++i)
        *(float4*)&w2r[i * 4] = *(const float4*)(w2 + c * 16 + i * 4);
    const float b2 = b2p[0];

    for (int b = wid; b < nb; b += 2 * nwav) {
        const int bB = b + nwav;
        const bool has2 = bB < nb;

        const int e0 = b * 4 + g;
        const int r0 = ei[e0];
        const int c0 = ei[E + e0];
        const int e1 = has2 ? bB * 4 + g : e0;
        const int r1 = ei[e1];
        const int c1 = ei[E + e1];

        uint4 ua = *(const uint4*)(uv + (size_t)r0 * 512 + c * 16);
        uint4 va = *(const uint4*)(uv + (size_t)c0 * 512 + 256 + c * 16);
        uint4 ub = *(const uint4*)(uv + (size_t)r1 * 512 + c * 16);
        uint4 vb = *(const uint4*)(uv + (size_t)c1 * 512 + 256 + c * 16);

        unsigned int uw[4], vw[4];
        float p;

        // ---- batch A ----
        *(uint4*)&uw[0] = ua; *(uint4*)&vw[0] = va;
        {
            float2 p2 = {0.f, 0.f};
#pragma unroll
            for (int w = 0; w < 4; ++w) {
                f32x2 u01 = __builtin_amdgcn_cvt_pk_f32_fp8(uw[w], false);
                f32x2 u23 = __builtin_amdgcn_cvt_pk_f32_fp8(uw[w], true);
                f32x2 v01 = __builtin_amdgcn_cvt_pk_f32_fp8(vw[w], false);
                f32x2 v23 = __builtin_amdgcn_cvt_pk_f32_fp8(vw[w], true);
                float s0 = fmaxf(u01.x + v01.x, 0.f);
                float s1 = fmaxf(u01.y + v01.y, 0.f);
                float s2 = fmaxf(u23.x + v23.x, 0.f);
                float s3 = fmaxf(u23.y + v23.y, 0.f);
                p2.x = fmaf(s0, w2r[4 * w + 0], p2.x);
                p2.y = fmaf(s1, w2r[4 * w + 1], p2.y);
                p2.x = fmaf(s2, w2r[4 * w + 2], p2.x);
                p2.y = fmaf(s3, w2r[4 * w + 3], p2.y);
            }
            p = p2.x + p2.y;
        }
#pragma unroll
        for (int off = 1; off < 16; off <<= 1)
            p += __shfl_xor(p, off, 64);
        if (c == 0) out[e0] = 1.f / (1.f + __expf(-(p + b2)));

        // ---- batch B ----
        if (has2) {
            *(uint4*)&uw[0] = ub; *(uint4*)&vw[0] = vb;
            float2 p2 = {0.f, 0.f};
#pragma unroll
            for (int w = 0; w < 4; ++w) {
                f32x2 u01 = __builtin_amdgcn_cvt_pk_f32_fp8(uw[w], false);
                f32x2 u23 = __builtin_amdgcn_cvt_pk_f32_fp8(uw[w], true);
                f32x2 v01 = __builtin_amdgcn_cvt_pk_f32_fp8(vw[w], false);
                f32x2 v23 = __builtin_amdgcn_cvt_pk_f32_fp8(vw[w], true);
                float s0 = fmaxf(u01.x + v01.x, 0.f);
                float s1 = fmaxf(u01.y + v01.y, 0.f);
                float s2 = fmaxf(u23.x + v23.x, 0.f);
                float s3 = fmaxf(u23.y + v23.y, 0.f);
                p2.x = fmaf(s0, w2r[4 * w + 0], p2.x);
                p2.y = fmaf(s1, w2r[4 * w + 1], p2.y);
                p2.x = fmaf(s2, w2r[4 * w + 2], p2.x);
                p2.y = fmaf(s3, w2r[4 * w + 3], p2.y);
            }
            p = p2.x + p2.y;
#pragma unroll
            for (int off = 1; off < 16; off <<= 1)
                p += __shfl_xor(p, off, 64);
            if (c == 0) out[e1] = 1.f / (1.f + __expf(-(p + b2)));
        }
    }
}

extern "C" void kernel_launch(void* const* d_in, const int* in_sizes, int n_in,
                              void* d_out, int out_size, void* d_ws, size_t ws_size,
                              hipStream_t stream) {
    const float* x  = (const float*)d_in[0];
    const int*   ei = (const int*)d_in[1];
    const float* W1 = (const float*)d_in[2];
    const float* b1 = (const float*)d_in[3];
    const float* W2 = (const float*)d_in[4];
    const float* b2 = (const float*)d_in[5];
    float* out = (float*)d_out;

    const int N = in_sizes[0] / 256;   // 10000
    const int E = in_sizes[1] / 2;     // 320000

    unsigned char* uv = (unsigned char*)d_ws;   // N*512 fp8 (5.12 MB)

    // 105 groups of 96 nodes (6 tiles of 16) x 2 k-halves = 210 blocks (<=256 CUs)
    const int ngrp = (N + 95) / 96;
    gemm_lds<<<ngrp * 2, 512, 0, stream>>>(x, W1, b1, uv, N);

    edge_kernel<<<2048, 256, 0, stream>>>(uv, ei, W2, b2, out, E);
}

// Round 6
// 107.949 us; speedup vs baseline: 1.0070x; 1.0070x over previous
//
#include <hip/hip_runtime.h>
#include <hip/hip_bf16.h>

// N=10000 nodes, F=256, H=256, E=320000 edges.
//
// W1 = [W1a | W1b]:  U' = x @ W1a^T + b1 (bias folded), V = x @ W1b^T
// out[e] = sigmoid(b2 + sum_j relu(U'[row][j] + V[col][j]) * W2[j])
// uv layout (fp8 e4m3, HW cvt): uv[node] = 512 bytes: [0:256]=U', [256:512]=V.
//
// R21 = R20 RESUBMITTED VERBATIM (R5 bench was an infra failure: "MI355X
// container failed twice" -- no compile/correctness signal; kernel unmeasured).
//
// R20 = gemm reverted to EXACT R18 (best: 106.2) + PACKED-F32 edge math.
//   Edge diagnosis: 25us x 256CU x 2.4GHz / 320k edges = 48 cyc/edge;
//   hot loop instr count (16 cvt + 16 add + 16 max + 16 fma = 64 wave-VALU
//   = 128 cyc per 4-edge batch -> 32 cyc/edge + reduce/addr/sigmoid) matches
//   -> edge kernel is VALU-BOUND (prior "L2 line-bound" was wrong; explains
//   R7 ILP-neutral). Fix: CDNA VOP3P packed f32 (v_pk_add_f32 / v_pk_fma_f32;
//   no pk_max). cvt_pk_f32_fp8 already yields f32x2 pairs -> vector add for
//   u+v, vector mul+add (contracts to pk_fma) for the W2-dot. Pairing
//   (s0,s1)/(s2,s3) preserves exact accumulation order (p2.x <- s0,s2;
//   p2.y <- s1,s3) -> bit-identical. Hot loop 64 -> 48 instrs (-25%).
//
// Journal: R6+R14 fused coop kernel -> 288/250us. R8/R9 sort -> too costly.
// R7 edge ILP -> neutral. R11 fp8 uv: -14.7us. R13: -3us. R15: 110.8.
// R16 folded-h 625x256: 115.3. R17 625x512: 114.9. R18 W1-in-LDS 252x1024,
// convert_w gone: 106.2 (BEST). R19 rebalanced 210x512: 108.7 (FAILED;
// changed 3 vars at once). Gemm restructuring is exhausted (4 rounds within
// noise); edge VALU is the remaining controllable lever.
// Harness tax ~47us fill/restores per window (not controllable).

typedef __attribute__((ext_vector_type(8))) short bf16x8;
typedef __attribute__((ext_vector_type(8))) unsigned short u16x8;
typedef __attribute__((ext_vector_type(4))) float f32x4;
typedef __attribute__((ext_vector_type(2))) float f32x2;

__device__ __forceinline__ unsigned short f2bf(float f) {
    __hip_bfloat16 h = __float2bfloat16(f);
    return *reinterpret_cast<unsigned short*>(&h);
}

// ---------------------------------------------------------------------------
// Kernel 1 (exact R18): grid 252 = 126 node-groups x 2 k-halves, 1024 thr.
// Phase 1: convert W1[0:256][h*256 : h*256+256] fp32 -> bf16 into LDS
//          Ws[256][264] (135.2 KB; row stride 264: 2-way alias = free).
// Phase 2: 20 tasks (5 tiles x 4 row-quarters), waves grid-stride (w, w+16).
//   Task (ti,q): nodes m0=(c*5+ti)*16, W1 rows r0=q*64.
//   W1-frag: Ws[r0 + j*16 + lm][kt*32 + lq*8]                (ds_read_b128)
//   x-frag:  x[m0+lm][kt*32 + lq*8 .. +7] fp32 -> cvt bf16   (2x dwordx4)
//   D: node = m0+lm; uv col = h*256 + r0 + j*16 + lq*4 + (0..3)
// Epilogue: bias (h==0) + 2x cvt_pk_fp8 -> one dword store per n-tile.
// ---------------------------------------------------------------------------
__global__ __launch_bounds__(1024) void gemm_lds(const float* __restrict__ x,
                                                 const float* __restrict__ w1,
                                                 const float* __restrict__ b1,
                                                 unsigned char* __restrict__ uv,
                                                 int M) {
    __shared__ __align__(16) unsigned short Ws[256][264];   // 135.2 KB

    const int t    = threadIdx.x;
    const int wave = t >> 6;
    const int lane = t & 63;
    const int lm   = lane & 15;
    const int lq   = lane >> 4;
    const int h    = blockIdx.x & 1;       // k-half
    const int c    = blockIdx.x >> 1;      // node group 0..125 (5 tiles each)

    // ---- phase 1: fill Ws. thread t: row t>>2, cols (t&3)*64 .. +63 ----
    {
        const int row = t >> 2;
        const int col = (t & 3) * 64;
        const float* wr = w1 + (size_t)row * 512 + h * 256 + col;
#pragma unroll
        for (int i = 0; i < 8; ++i) {      // 8 floats -> one 16B LDS write
            float4 a = *(const float4*)(wr + i * 8);
            float4 b = *(const float4*)(wr + i * 8 + 4);
            u16x8 o = {f2bf(a.x), f2bf(a.y), f2bf(a.z), f2bf(a.w),
                       f2bf(b.x), f2bf(b.y), f2bf(b.z), f2bf(b.w)};
            *(u16x8*)&Ws[row][col + i * 8] = o;
        }
    }
    __syncthreads();

    // ---- phase 2: 20 tasks over 16 waves, barrier-free ----
    for (int id = wave; id < 20; id += 16) {
        const int ti = id >> 2;            // tile in group, 0..4
        const int q  = id & 3;             // row quarter
        const int m0 = (c * 5 + ti) * 16;  // node base
        const int r0 = q * 64;             // W1 row base

        const int gr = m0 + lm;
        const float* xr = x + (size_t)(gr < M ? gr : (M - 1)) * 256 + lq * 8;

        f32x4 acc[4];
#pragma unroll
        for (int j = 0; j < 4; ++j) acc[j] = f32x4{0.f, 0.f, 0.f, 0.f};

#pragma unroll
        for (int kt = 0; kt < 8; ++kt) {
            float4 a = *(const float4*)(xr + kt * 32);
            float4 b = *(const float4*)(xr + kt * 32 + 4);
            bf16x8 xf;
            xf[0] = (short)f2bf(a.x); xf[1] = (short)f2bf(a.y);
            xf[2] = (short)f2bf(a.z); xf[3] = (short)f2bf(a.w);
            xf[4] = (short)f2bf(b.x); xf[5] = (short)f2bf(b.y);
            xf[6] = (short)f2bf(b.z); xf[7] = (short)f2bf(b.w);
#pragma unroll
            for (int j = 0; j < 4; ++j) {
                bf16x8 wf = *(const bf16x8*)&Ws[r0 + j * 16 + lm][kt * 32 + lq * 8];
                // swapped: A = W1 (m = uv col), B = x (n = node)
                acc[j] = __builtin_amdgcn_mfma_f32_16x16x32_bf16(wf, xf, acc[j], 0, 0, 0);
            }
        }

        // ---- epilogue: 4 consecutive uv cols per n-tile -> dword store ----
        const int node = m0 + lm;
        if (node < M) {
            unsigned char* up = uv + (size_t)node * 512 + h * 256 + r0 + lq * 4;
#pragma unroll
            for (int j = 0; j < 4; ++j) {
                float4 bb = (h == 0)
                              ? *(const float4*)(b1 + r0 + j * 16 + lq * 4)
                              : float4{0.f, 0.f, 0.f, 0.f};
                unsigned int d = __builtin_amdgcn_cvt_pk_fp8_f32(
                    acc[j][0] + bb.x, acc[j][1] + bb.y, 0, false);
                d = __builtin_amdgcn_cvt_pk_fp8_f32(
                    acc[j][2] + bb.z, acc[j][3] + bb.w, d, true);
                *(unsigned int*)(up + j * 16) = d;
            }
        }
    }
}

// ---------------------------------------------------------------------------
// Kernel 2 (R20): edge phase over fp8 uv, PACKED-F32 math.
// 4 edges/batch (g=lane>>4 slot, c=lane&15 col chunk); per lane one uint4
// (16 fp8) per U row + one per V row; two independent batches/iteration.
// Hot loop per dword w: 4 cvt_pk + 2 pk_add + 4 v_max + 2 pk_fma
// (was 4 cvt + 4 add + 4 max + 4 fma). Accumulation order preserved:
// p2.x <- s0,s2 ; p2.y <- s1,s3  (bit-identical to R11-R19).
// ---------------------------------------------------------------------------
__global__ __launch_bounds__(256) void edge_kernel(const unsigned char* __restrict__ uv,
                                                   const int* __restrict__ ei,
                                                   const float* __restrict__ w2,
                                                   const float* __restrict__ b2p,
                                                   float* __restrict__ out, int E) {
    const int lane = threadIdx.x & 63;
    const int g = lane >> 4;
    const int c = lane & 15;
    const int wid  = (blockIdx.x * blockDim.x + threadIdx.x) >> 6;
    const int nwav = (gridDim.x * blockDim.x) >> 6;
    const int nb   = E >> 2;

    float w2r[16];
#pragma unroll
    for (int i = 0; i < 4; ++i)
        *(float4*)&w2r[i * 4] = *(const float4*)(w2 + c * 16 + i * 4);
    const float b2 = b2p[0];

    for (int b = wid; b < nb; b += 2 * nwav) {
        const int bB = b + nwav;
        const bool has2 = bB < nb;

        const int e0 = b * 4 + g;
        const int r0 = ei[e0];
        const int c0 = ei[E + e0];
        const int e1 = has2 ? bB * 4 + g : e0;
        const int r1 = ei[e1];
        const int c1 = ei[E + e1];

        uint4 ua = *(const uint4*)(uv + (size_t)r0 * 512 + c * 16);
        uint4 va = *(const uint4*)(uv + (size_t)c0 * 512 + 256 + c * 16);
        uint4 ub = *(const uint4*)(uv + (size_t)r1 * 512 + c * 16);
        uint4 vb = *(const uint4*)(uv + (size_t)c1 * 512 + 256 + c * 16);

        unsigned int uw[4], vw[4];
        float p;

        // ---- batch A ----
        *(uint4*)&uw[0] = ua; *(uint4*)&vw[0] = va;
        {
            f32x2 p2 = {0.f, 0.f};
#pragma unroll
            for (int w = 0; w < 4; ++w) {
                f32x2 u01 = __builtin_amdgcn_cvt_pk_f32_fp8(uw[w], false);
                f32x2 u23 = __builtin_amdgcn_cvt_pk_f32_fp8(uw[w], true);
                f32x2 v01 = __builtin_amdgcn_cvt_pk_f32_fp8(vw[w], false);
                f32x2 v23 = __builtin_amdgcn_cvt_pk_f32_fp8(vw[w], true);
                f32x2 a01 = u01 + v01;                       // v_pk_add_f32
                f32x2 a23 = u23 + v23;                       // v_pk_add_f32
                f32x2 s01 = {fmaxf(a01[0], 0.f), fmaxf(a01[1], 0.f)};
                f32x2 s23 = {fmaxf(a23[0], 0.f), fmaxf(a23[1], 0.f)};
                f32x2 w01 = {w2r[4 * w + 0], w2r[4 * w + 1]};
                f32x2 w23 = {w2r[4 * w + 2], w2r[4 * w + 3]};
                p2 = s01 * w01 + p2;                         // v_pk_fma_f32
                p2 = s23 * w23 + p2;                         // v_pk_fma_f32
            }
            p = p2[0] + p2[1];
        }
#pragma unroll
        for (int off = 1; off < 16; off <<= 1)
            p += __shfl_xor(p, off, 64);
        if (c == 0) out[e0] = 1.f / (1.f + __expf(-(p + b2)));

        // ---- batch B ----
        if (has2) {
            *(uint4*)&uw[0] = ub; *(uint4*)&vw[0] = vb;
            f32x2 p2 = {0.f, 0.f};
#pragma unroll
            for (int w = 0; w < 4; ++w) {
                f32x2 u01 = __builtin_amdgcn_cvt_pk_f32_fp8(uw[w], false);
                f32x2 u23 = __builtin_amdgcn_cvt_pk_f32_fp8(uw[w], true);
                f32x2 v01 = __builtin_amdgcn_cvt_pk_f32_fp8(vw[w], false);
                f32x2 v23 = __builtin_amdgcn_cvt_pk_f32_fp8(vw[w], true);
                f32x2 a01 = u01 + v01;
                f32x2 a23 = u23 + v23;
                f32x2 s01 = {fmaxf(a01[0], 0.f), fmaxf(a01[1], 0.f)};
                f32x2 s23 = {fmaxf(a23[0], 0.f), fmaxf(a23[1], 0.f)};
                f32x2 w01 = {w2r[4 * w + 0], w2r[4 * w + 1]};
                f32x2 w23 = {w2r[4 * w + 2], w2r[4 * w + 3]};
                p2 = s01 * w01 + p2;
                p2 = s23 * w23 + p2;
            }
            p = p2[0] + p2[1];
#pragma unroll
            for (int off = 1; off < 16; off <<= 1)
                p += __shfl_xor(p, off, 64);
            if (c == 0) out[e1] = 1.f / (1.f + __expf(-(p + b2)));
        }
    }
}

extern "C" void kernel_launch(void* const* d_in, const int* in_sizes, int n_in,
                              void* d_out, int out_size, void* d_ws, size_t ws_size,
                              hipStream_t stream) {
    const float* x  = (const float*)d_in[0];
    const int*   ei = (const int*)d_in[1];
    const float* W1 = (const float*)d_in[2];
    const float* b1 = (const float*)d_in[3];
    const float* W2 = (const float*)d_in[4];
    const float* b2 = (const float*)d_in[5];
    float* out = (float*)d_out;

    const int N = in_sizes[0] / 256;   // 10000
    const int E = in_sizes[1] / 2;     // 320000

    unsigned char* uv = (unsigned char*)d_ws;   // N*512 fp8 (5.12 MB)

    // 126 node-groups (5 tiles of 16 = 80 nodes each) x 2 halves = 252 blocks
    const int ngrp = (N + 79) / 80;
    gemm_lds<<<ngrp * 2, 1024, 0, stream>>>(x, W1, b1, uv, N);

    edge_kernel<<<2048, 256, 0, stream>>>(uv, ei, W2, b2, out, E);
}

// Round 7
// 106.291 us; speedup vs baseline: 1.0227x; 1.0156x over previous
//
#include <hip/hip_runtime.h>
#include <hip/hip_bf16.h>

// N=10000 nodes, F=256, H=256, E=320000 edges.
//
// W1 = [W1a | W1b]:  U' = x @ W1a^T + b1 (bias folded), V = x @ W1b^T
// out[e] = sigmoid(b2 + sum_j relu(U'[row][j] + V[col][j]) * W2[j])
// uv layout (fp8 e4m3, HW cvt): uv[node] = 512 bytes: [0:256]=U', [256:512]=V.
//
// R22 = EXACT R18 RESTORED (best measured: 106.2us). R20/R21's packed-f32
// edge math was neutral (107.9, within +-2us harness noise) -> edge is NOT
// VALU-bound (issue cost ~16% of its 192 SIMD-cyc/edge; it is gather-
// latency/memory-system-bound and structural). Reverting the neutral change
// to lock the best-measured config.
//
// CLOSED LEVERS (all measured): gemm restructure x4 (R16/17/19 regressed,
// R18 won via convert_w-elim only); fusion (R6/R14: 250-288us); sort
// (R8/R9: cost >> gain); edge ILP (R7 neutral); edge VALU pack (R20
// neutral). Real wins ever: fp8 uv -14.7us, W1-in-LDS + convert_w-elim
// -4.6us. Budget: ~47us harness fill tax + ~14us gemm (x-HBM/convert
// floor) + ~25us edge (gather floor) + ~5us gaps = ~106us = practical
// roofline for this 3-kernel structure.

typedef __attribute__((ext_vector_type(8))) short bf16x8;
typedef __attribute__((ext_vector_type(8))) unsigned short u16x8;
typedef __attribute__((ext_vector_type(4))) float f32x4;
typedef __attribute__((ext_vector_type(2))) float f32x2;

__device__ __forceinline__ unsigned short f2bf(float f) {
    __hip_bfloat16 h = __float2bfloat16(f);
    return *reinterpret_cast<unsigned short*>(&h);
}

// ---------------------------------------------------------------------------
// Kernel 1 (exact R18): grid 252 = 126 node-groups x 2 k-halves, 1024 thr.
// Phase 1: convert W1[0:256][h*256 : h*256+256] fp32 -> bf16 into LDS
//          Ws[256][264] (135.2 KB; row stride 264: 2-way alias = free).
// Phase 2: 20 tasks (5 tiles x 4 row-quarters), waves grid-stride (w, w+16).
//   Task (ti,q): nodes m0=(c*5+ti)*16, W1 rows r0=q*64.
//   W1-frag: Ws[r0 + j*16 + lm][kt*32 + lq*8]                (ds_read_b128)
//   x-frag:  x[m0+lm][kt*32 + lq*8 .. +7] fp32 -> cvt bf16   (2x dwordx4)
//   D: node = m0+lm; uv col = h*256 + r0 + j*16 + lq*4 + (0..3)
// Epilogue: bias (h==0) + 2x cvt_pk_fp8 -> one dword store per n-tile.
// ---------------------------------------------------------------------------
__global__ __launch_bounds__(1024) void gemm_lds(const float* __restrict__ x,
                                                 const float* __restrict__ w1,
                                                 const float* __restrict__ b1,
                                                 unsigned char* __restrict__ uv,
                                                 int M) {
    __shared__ __align__(16) unsigned short Ws[256][264];   // 135.2 KB

    const int t    = threadIdx.x;
    const int wave = t >> 6;
    const int lane = t & 63;
    const int lm   = lane & 15;
    const int lq   = lane >> 4;
    const int h    = blockIdx.x & 1;       // k-half
    const int c    = blockIdx.x >> 1;      // node group 0..125 (5 tiles each)

    // ---- phase 1: fill Ws. thread t: row t>>2, cols (t&3)*64 .. +63 ----
    {
        const int row = t >> 2;
        const int col = (t & 3) * 64;
        const float* wr = w1 + (size_t)row * 512 + h * 256 + col;
#pragma unroll
        for (int i = 0; i < 8; ++i) {      // 8 floats -> one 16B LDS write
            float4 a = *(const float4*)(wr + i * 8);
            float4 b = *(const float4*)(wr + i * 8 + 4);
            u16x8 o = {f2bf(a.x), f2bf(a.y), f2bf(a.z), f2bf(a.w),
                       f2bf(b.x), f2bf(b.y), f2bf(b.z), f2bf(b.w)};
            *(u16x8*)&Ws[row][col + i * 8] = o;
        }
    }
    __syncthreads();

    // ---- phase 2: 20 tasks over 16 waves, barrier-free ----
    for (int id = wave; id < 20; id += 16) {
        const int ti = id >> 2;            // tile in group, 0..4
        const int q  = id & 3;             // row quarter
        const int m0 = (c * 5 + ti) * 16;  // node base
        const int r0 = q * 64;             // W1 row base

        const int gr = m0 + lm;
        const float* xr = x + (size_t)(gr < M ? gr : (M - 1)) * 256 + lq * 8;

        f32x4 acc[4];
#pragma unroll
        for (int j = 0; j < 4; ++j) acc[j] = f32x4{0.f, 0.f, 0.f, 0.f};

#pragma unroll
        for (int kt = 0; kt < 8; ++kt) {
            float4 a = *(const float4*)(xr + kt * 32);
            float4 b = *(const float4*)(xr + kt * 32 + 4);
            bf16x8 xf;
            xf[0] = (short)f2bf(a.x); xf[1] = (short)f2bf(a.y);
            xf[2] = (short)f2bf(a.z); xf[3] = (short)f2bf(a.w);
            xf[4] = (short)f2bf(b.x); xf[5] = (short)f2bf(b.y);
            xf[6] = (short)f2bf(b.z); xf[7] = (short)f2bf(b.w);
#pragma unroll
            for (int j = 0; j < 4; ++j) {
                bf16x8 wf = *(const bf16x8*)&Ws[r0 + j * 16 + lm][kt * 32 + lq * 8];
                // swapped: A = W1 (m = uv col), B = x (n = node)
                acc[j] = __builtin_amdgcn_mfma_f32_16x16x32_bf16(wf, xf, acc[j], 0, 0, 0);
            }
        }

        // ---- epilogue: 4 consecutive uv cols per n-tile -> dword store ----
        const int node = m0 + lm;
        if (node < M) {
            unsigned char* up = uv + (size_t)node * 512 + h * 256 + r0 + lq * 4;
#pragma unroll
            for (int j = 0; j < 4; ++j) {
                float4 bb = (h == 0)
                              ? *(const float4*)(b1 + r0 + j * 16 + lq * 4)
                              : float4{0.f, 0.f, 0.f, 0.f};
                unsigned int d = __builtin_amdgcn_cvt_pk_fp8_f32(
                    acc[j][0] + bb.x, acc[j][1] + bb.y, 0, false);
                d = __builtin_amdgcn_cvt_pk_fp8_f32(
                    acc[j][2] + bb.z, acc[j][3] + bb.w, d, true);
                *(unsigned int*)(up + j * 16) = d;
            }
        }
    }
}

// ---------------------------------------------------------------------------
// Kernel 2 (R11 scalar form, exact R18 pairing): edge phase over fp8 uv.
// 4 edges/batch (g=lane>>4 slot, c=lane&15 col chunk); per lane one uint4
// (16 fp8) per U row + one per V row; two independent batches per
// iteration; HW decode. Gather-latency-bound (structural floor).
// ---------------------------------------------------------------------------
__global__ __launch_bounds__(256) void edge_kernel(const unsigned char* __restrict__ uv,
                                                   const int* __restrict__ ei,
                                                   const float* __restrict__ w2,
                                                   const float* __restrict__ b2p,
                                                   float* __restrict__ out, int E) {
    const int lane = threadIdx.x & 63;
    const int g = lane >> 4;
    const int c = lane & 15;
    const int wid  = (blockIdx.x * blockDim.x + threadIdx.x) >> 6;
    const int nwav = (gridDim.x * blockDim.x) >> 6;
    const int nb   = E >> 2;

    float w2r[16];
#pragma unroll
    for (int i = 0; i < 4; ++i)
        *(float4*)&w2r[i * 4] = *(const float4*)(w2 + c * 16 + i * 4);
    const float b2 = b2p[0];

    for (int b = wid; b < nb; b += 2 * nwav) {
        const int bB = b + nwav;
        const bool has2 = bB < nb;

        const int e0 = b * 4 + g;
        const int r0 = ei[e0];
        const int c0 = ei[E + e0];
        const int e1 = has2 ? bB * 4 + g : e0;
        const int r1 = ei[e1];
        const int c1 = ei[E + e1];

        uint4 ua = *(const uint4*)(uv + (size_t)r0 * 512 + c * 16);
        uint4 va = *(const uint4*)(uv + (size_t)c0 * 512 + 256 + c * 16);
        uint4 ub = *(const uint4*)(uv + (size_t)r1 * 512 + c * 16);
        uint4 vb = *(const uint4*)(uv + (size_t)c1 * 512 + 256 + c * 16);

        unsigned int uw[4], vw[4];
        float p;

        // ---- batch A ----
        *(uint4*)&uw[0] = ua; *(uint4*)&vw[0] = va;
        {
            float2 p2 = {0.f, 0.f};
#pragma unroll
            for (int w = 0; w < 4; ++w) {
                f32x2 u01 = __builtin_amdgcn_cvt_pk_f32_fp8(uw[w], false);
                f32x2 u23 = __builtin_amdgcn_cvt_pk_f32_fp8(uw[w], true);
                f32x2 v01 = __builtin_amdgcn_cvt_pk_f32_fp8(vw[w], false);
                f32x2 v23 = __builtin_amdgcn_cvt_pk_f32_fp8(vw[w], true);
                float s0 = fmaxf(u01.x + v01.x, 0.f);
                float s1 = fmaxf(u01.y + v01.y, 0.f);
                float s2 = fmaxf(u23.x + v23.x, 0.f);
                float s3 = fmaxf(u23.y + v23.y, 0.f);
                p2.x = fmaf(s0, w2r[4 * w + 0], p2.x);
                p2.y = fmaf(s1, w2r[4 * w + 1], p2.y);
                p2.x = fmaf(s2, w2r[4 * w + 2], p2.x);
                p2.y = fmaf(s3, w2r[4 * w + 3], p2.y);
            }
            p = p2.x + p2.y;
        }
#pragma unroll
        for (int off = 1; off < 16; off <<= 1)
            p += __shfl_xor(p, off, 64);
        if (c == 0) out[e0] = 1.f / (1.f + __expf(-(p + b2)));

        // ---- batch B ----
        if (has2) {
            *(uint4*)&uw[0] = ub; *(uint4*)&vw[0] = vb;
            float2 p2 = {0.f, 0.f};
#pragma unroll
            for (int w = 0; w < 4; ++w) {
                f32x2 u01 = __builtin_amdgcn_cvt_pk_f32_fp8(uw[w], false);
                f32x2 u23 = __builtin_amdgcn_cvt_pk_f32_fp8(uw[w], true);
                f32x2 v01 = __builtin_amdgcn_cvt_pk_f32_fp8(vw[w], false);
                f32x2 v23 = __builtin_amdgcn_cvt_pk_f32_fp8(vw[w], true);
                float s0 = fmaxf(u01.x + v01.x, 0.f);
                float s1 = fmaxf(u01.y + v01.y, 0.f);
                float s2 = fmaxf(u23.x + v23.x, 0.f);
                float s3 = fmaxf(u23.y + v23.y, 0.f);
                p2.x = fmaf(s0, w2r[4 * w + 0], p2.x);
                p2.y = fmaf(s1, w2r[4 * w + 1], p2.y);
                p2.x = fmaf(s2, w2r[4 * w + 2], p2.x);
                p2.y = fmaf(s3, w2r[4 * w + 3], p2.y);
            }
            p = p2.x + p2.y;
#pragma unroll
            for (int off = 1; off < 16; off <<= 1)
                p += __shfl_xor(p, off, 64);
            if (c == 0) out[e1] = 1.f / (1.f + __expf(-(p + b2)));
        }
    }
}

extern "C" void kernel_launch(void* const* d_in, const int* in_sizes, int n_in,
                              void* d_out, int out_size, void* d_ws, size_t ws_size,
                              hipStream_t stream) {
    const float* x  = (const float*)d_in[0];
    const int*   ei = (const int*)d_in[1];
    const float* W1 = (const float*)d_in[2];
    const float* b1 = (const float*)d_in[3];
    const float* W2 = (const float*)d_in[4];
    const float* b2 = (const float*)d_in[5];
    float* out = (float*)d_out;

    const int N = in_sizes[0] / 256;   // 10000
    const int E = in_sizes[1] / 2;     // 320000

    unsigned char* uv = (unsigned char*)d_ws;   // N*512 fp8 (5.12 MB)

    // 126 node-groups (5 tiles of 16 = 80 nodes each) x 2 halves = 252 blocks
    const int ngrp = (N + 79) / 80;
    gemm_lds<<<ngrp * 2, 1024, 0, stream>>>(x, W1, b1, uv, N);

    edge_kernel<<<2048, 256, 0, stream>>>(uv, ei, W2, b2, out, E);
}